// Round 1
// baseline (144.025 us; speedup 1.0000x reference)
//
#include <hip/hip_runtime.h>
#include <stdint.h>

// CSWin attention, MI355X/gfx950 — r10: occupancy 3->4 blocks/CU.
// Shapes: B=2, H=W=64, N=4, DIM=128, HEADS=4, HEAD_DIM=32, SPLIT=2.
// 64 windows x 4 heads, L=512 tokens, D=32. Grid 1024 = (window,head) x 4
// row-quarters; block 256 (4 waves); wave = 32 q-rows (2 m-tiles).
//
// r10 theory: r9 counters were latency/occupancy-bound (VALUBusy 48%,
// MfmaUtil 5%, HBM 12%, Occupancy 22%). LDS 51200B capped residency at
// 3 blocks/CU while the 1024-block grid needs exactly 4/CU -> 25% tail
// round + thin latency hiding. Changes:
//  * S (rpe neighbor sums) no longer materialized: recomputed in the
//    epilogue directly from VT (4 bf16 adds per neighbor) — deletes the
//    S stage, its __syncthreads and 8704B LDS. f32 sum (was bf16-rounded).
//  * VT unpadded [32][512], XOR-swizzled (in-row dword ^ ((row&7)<<2)).
//    All accesses are dword-or-coarser with 4-aligned uint4 bases, so the
//    bits>=2 XOR preserves access contiguity; bank spread <=2-way (free).
//  * PB unpadded [16][64]/wave, same swizzle — kills the 4-way bank
//    conflict on P writes (bank 4n+2qd) that was the bulk of the 2.4M
//    SQ_LDS_BANK_CONFLICT.
//  * Total LDS 40960 == 160KiB/4 -> 4 blocks/CU, whole grid resident.
// Predicted: Occupancy ~40, VALUBusy 60-70%, conflicts <0.4M, dur ~42us.

typedef __bf16 bf16x8 __attribute__((ext_vector_type(8)));
typedef float f32x4 __attribute__((ext_vector_type(4)));

#if __has_builtin(__builtin_amdgcn_exp2f)
#define EXP2F __builtin_amdgcn_exp2f
#else
#define EXP2F exp2f
#endif

union U4 { uint4 u; bf16x8 v; unsigned short s[8]; };

__device__ __forceinline__ unsigned fbits(float f){ union{float f;unsigned u;}x; x.f=f; return x.u; }
__device__ __forceinline__ float bf2f(unsigned short h){ union{unsigned u;float f;}x; x.u=((unsigned)h)<<16; return x.f; }
// f32->bf16 round-nearest (ties away), two at once: 2 v_add + 1 v_perm
__device__ __forceinline__ unsigned pk2f(float lo, float hi){
  return __builtin_amdgcn_perm(fbits(hi)+0x8000u, fbits(lo)+0x8000u, 0x07060302u);
}
__device__ __forceinline__ U4 pack8(float4 a, float4 b){
  U4 r;
  r.u.x = pk2f(a.x, a.y); r.u.y = pk2f(a.z, a.w);
  r.u.z = pk2f(b.x, b.y); r.u.w = pk2f(b.z, b.w);
  return r;
}

#define C_SCALE 0.25506953149031837f  // (1/sqrt(32)) * log2(e)
#define M_SHIFT 20.0f                 // fixed log2-domain softmax shift

// LDS: VT bf16 [32 ch][512 tok] swizzled, 1024B/row @0      (32768)
//      PB bf16 [16][64] swizzled, 2048B x 4 waves @32768    ( 8192)
//      total 40960 => 4 blocks/CU
#define VT_OFF 0
#define PB_OFF 32768
#define LDS_BYTES 40960

__global__ __launch_bounds__(256, 4) void cswin_attn_kernel(
    const float* __restrict__ qg,
    const float* __restrict__ kg,
    const float* __restrict__ vg,
    const float* __restrict__ cwg,
    float* __restrict__ outg)
{
  __shared__ __align__(16) unsigned char smem[LDS_BYTES];
  const int tid = threadIdx.x;
  const int lane = tid & 63;
  const int wave = tid >> 6;
  const int qd = lane >> 4;
  const int n  = lane & 15;

  // swizzle constants: in-row dword index ^= (row&7)<<2. All hot rows for
  // this lane are ( n mod 8 )-congruent (n, n+16, nt*16+n), so one mask.
  const int swn = (n & 7) << 2;
  const int xb0 = ((4 * qd) ^ swn) << 2;   // byte off of swizzled dword 4qd
  const int xb1 = xb0 ^ 64;                // ... of dword 16+4qd

  const int bh = blockIdx.x & 255;
  const int q4 = blockIdx.x >> 8;     // row-quarter 0..3
  const int head = bh & 3;
  const int bw = bh >> 2;
  const int b  = bw >> 5;
  const int jj = bw & 31;

  // token l: offset = wbase + (l>>3)*32768 + ((l>>2)&1)*512 + (l&3)*128
  const size_t wbase = (size_t)b * 2097152 + (size_t)(jj * 2) * 512 + head * 32;

  // ---- stage V -> VT bf16 (2 tokens per thread, packed pairwise) ----
  {
    int l0 = tid * 2;
    size_t off = wbase + (size_t)(l0 >> 3) * 32768 + (size_t)((l0 >> 2) & 1) * 512 + (l0 & 3) * 128;
    const float* p0 = vg + off;
    unsigned u0[32], u1[32];
#pragma unroll
    for (int c = 0; c < 8; c++){
      float4 a = ((const float4*)p0)[c];
      u0[c*4+0]=fbits(a.x)+0x8000u; u0[c*4+1]=fbits(a.y)+0x8000u;
      u0[c*4+2]=fbits(a.z)+0x8000u; u0[c*4+3]=fbits(a.w)+0x8000u;
    }
#pragma unroll
    for (int c = 0; c < 8; c++){
      float4 a = ((const float4*)(p0 + 128))[c];
      u1[c*4+0]=fbits(a.x)+0x8000u; u1[c*4+1]=fbits(a.y)+0x8000u;
      u1[c*4+2]=fbits(a.z)+0x8000u; u1[c*4+3]=fbits(a.w)+0x8000u;
    }
    // logical dword col = tid (token pair 2*tid, 2*tid+1), row = d
#pragma unroll
    for (int d = 0; d < 32; d++)
      *(unsigned*)(smem + VT_OFF + d * 1024 + ((tid ^ ((d & 7) << 2)) << 2)) =
          __builtin_amdgcn_perm(u1[d], u0[d], 0x07060302u);
  }
  __syncthreads();

  // per-lane elem base for Q/K fragments (token tile*16+n, channels qd*8..+7)
  const size_t lane_base = wbase + (size_t)(n >> 3) * 32768 + (size_t)((n >> 2) & 1) * 512 +
                           (size_t)(n & 3) * 128 + qd * 8;

  const int row0  = q4 * 128 + wave * 32;
  const int tilea = row0 >> 4;          // even; m-tile B = tilea+1
  const int cka   = tilea >> 2;         // chunk holding both diag tiles
  const int ta    = tilea & 3;          // in-chunk tile idx of A's diag

  U4 bqa, bqb;
  {
    const float* qa = qg + lane_base + (size_t)tilea * 65536;
    const float* qb = qa + 65536;
    bqa = pack8(((const float4*)qa)[0], ((const float4*)qa)[1]);
    bqb = pack8(((const float4*)qb)[0], ((const float4*)qb)[1]);
  }

  f32x4 o0a={0,0,0,0}, o1a={0,0,0,0}, o0b={0,0,0,0}, o1b={0,0,0,0};
  float la = 0.f, lb = 0.f;            // per-lane partial softmax sums

  unsigned char* PBb = smem + PB_OFF + wave * 2048 + n * 128;

  // prefetch chunk 0 K rows (raw f32; packed at use)
  float4 nxt[8];
#pragma unroll
  for (int t = 0; t < 4; t++){
    const float* kp = kg + lane_base + (size_t)t * 65536;
    nxt[2*t] = ((const float4*)kp)[0]; nxt[2*t+1] = ((const float4*)kp)[1];
  }

#pragma unroll 1
  for (int ck = 0; ck < 8; ck++){
    U4 ak[4];
#pragma unroll
    for (int t = 0; t < 4; t++) ak[t] = pack8(nxt[2*t], nxt[2*t+1]);
    if (ck < 7){
#pragma unroll
      for (int t = 0; t < 4; t++){
        const float* kp = kg + lane_base + (size_t)((ck + 1) * 4 + t) * 65536;
        nxt[2*t] = ((const float4*)kp)[0]; nxt[2*t+1] = ((const float4*)kp)[1];
      }
    }

    const f32x4 zero = {0.f,0.f,0.f,0.f};
    f32x4 sa[4], sb[4];
#pragma unroll
    for (int t = 0; t < 4; t++){
      sa[t] = __builtin_amdgcn_mfma_f32_16x16x32_bf16(ak[t].v, bqa.v, zero, 0, 0, 0);
      sb[t] = __builtin_amdgcn_mfma_f32_16x16x32_bf16(ak[t].v, bqb.v, zero, 0, 0, 0);
    }
    if (ck == cka){
      bool dq = (qd == (n >> 2));
#pragma unroll
      for (int r = 0; r < 4; r++)
        if (dq && r != (n & 3)){ sa[ta][r] = -1e30f; sb[ta+1][r] = -1e30f; }
    }

    // ---- fixed-shift softmax: p = exp2(s*C - M); accumulate per-lane l ----
#pragma unroll
    for (int t = 0; t < 4; t++)
#pragma unroll
      for (int r = 0; r < 4; r++){
        float p = EXP2F(__builtin_fmaf(sa[t][r], C_SCALE, -M_SHIFT));
        sa[t][r] = p; la += p;
      }
#pragma unroll
    for (int t = 0; t < 4; t++)
#pragma unroll
      for (int r = 0; r < 4; r++){
        float p = EXP2F(__builtin_fmaf(sb[t][r], C_SCALE, -M_SHIFT));
        sb[t][r] = p; lb += p;
      }

    // ---- V fragments shared by both m-tiles (swizzled VT reads) ----
    const unsigned char* vr0 = smem + VT_OFF + n * 1024 + ck * 128;
    const unsigned char* vr1 = vr0 + 16 * 1024;
    U4 bv00, bv01, bv10, bv11;
    bv00.u = *(const uint4*)(vr0 + xb0);
    bv01.u = *(const uint4*)(vr0 + xb1);
    bv10.u = *(const uint4*)(vr1 + xb0);
    bv11.u = *(const uint4*)(vr1 + xb1);

    // m-tile A: pack P -> PB -> A-fragments (per-wave buffer, in-order DS)
#pragma unroll
    for (int tl = 0; tl < 4; tl++){
      uint2 w2; w2.x = pk2f(sa[tl][0], sa[tl][1]); w2.y = pk2f(sa[tl][2], sa[tl][3]);
      *(uint2*)(PBb + (((8 * tl + 2 * qd) ^ swn) << 2)) = w2;
    }
    __builtin_amdgcn_wave_barrier();
    U4 apA0, apA1;
    apA0.u = *(const uint4*)(PBb + xb0);
    apA1.u = *(const uint4*)(PBb + xb1);
    __builtin_amdgcn_wave_barrier();
    // m-tile B reuses the buffer
#pragma unroll
    for (int tl = 0; tl < 4; tl++){
      uint2 w2; w2.x = pk2f(sb[tl][0], sb[tl][1]); w2.y = pk2f(sb[tl][2], sb[tl][3]);
      *(uint2*)(PBb + (((8 * tl + 2 * qd) ^ swn) << 2)) = w2;
    }
    __builtin_amdgcn_wave_barrier();
    U4 apB0, apB1;
    apB0.u = *(const uint4*)(PBb + xb0);
    apB1.u = *(const uint4*)(PBb + xb1);
    __builtin_amdgcn_wave_barrier();  // pin next-iter PB writes behind apB reads

    o0a = __builtin_amdgcn_mfma_f32_16x16x32_bf16(apA0.v, bv00.v, o0a, 0, 0, 0);
    o0a = __builtin_amdgcn_mfma_f32_16x16x32_bf16(apA1.v, bv01.v, o0a, 0, 0, 0);
    o1a = __builtin_amdgcn_mfma_f32_16x16x32_bf16(apA0.v, bv10.v, o1a, 0, 0, 0);
    o1a = __builtin_amdgcn_mfma_f32_16x16x32_bf16(apA1.v, bv11.v, o1a, 0, 0, 0);
    o0b = __builtin_amdgcn_mfma_f32_16x16x32_bf16(apB0.v, bv00.v, o0b, 0, 0, 0);
    o0b = __builtin_amdgcn_mfma_f32_16x16x32_bf16(apB1.v, bv01.v, o0b, 0, 0, 0);
    o1b = __builtin_amdgcn_mfma_f32_16x16x32_bf16(apB0.v, bv10.v, o1b, 0, 0, 0);
    o1b = __builtin_amdgcn_mfma_f32_16x16x32_bf16(apB1.v, bv11.v, o1b, 0, 0, 0);
  }

  // ---- conv weights (global loads issue before/overlap the DS reduce) ----
  float w9[2][9];
#pragma unroll
  for (int nt = 0; nt < 2; nt++){
    int c = head * 32 + nt * 16 + n;
#pragma unroll
    for (int t9 = 0; t9 < 9; t9++) w9[nt][t9] = cwg[c * 9 + t9];
  }

  // ---- final cross-lane l reduction (once, not per chunk) ----
  la += __shfl_xor(la, 16); la += __shfl_xor(la, 32);
  lb += __shfl_xor(lb, 16); lb += __shfl_xor(lb, 32);

  const float ila = 1.f / la, ilb = 1.f / lb;

  // ---- epilogue for both m-tiles (S recomputed from VT on the fly) ----
#pragma unroll
  for (int mt = 0; mt < 2; mt++){
    const int m0 = row0 + mt * 16;
    const float ilv = mt ? ilb : ila;
    const f32x4 oo0 = mt ? o0b : o0a;
    const f32x4 oo1 = mt ? o1b : o1a;
    float il[4];
#pragma unroll
    for (int r = 0; r < 4; r++) il[r] = __shfl(ilv, qd * 4 + r);

    const int sp = (m0 >> 2) + qd;
    const int h_ = sp >> 1, w_ = sp & 1;
#pragma unroll
    for (int nt = 0; nt < 2; nt++){
      const int d = nt * 16 + n;
      const unsigned char* VTd = smem + VT_OFF + d * 1024;   // (d&7)==(n&7)
      float acc = 0.f;
#pragma unroll
      for (int dy = -1; dy <= 1; dy++){
        int h2 = h_ + dy;
        bool hv = (h2 >= 0) && (h2 <= 63);
        int h2c = hv ? h2 : h_;   // safe in-range address for masked lanes
#pragma unroll
        for (int wp = 0; wp < 2; wp++){
          bool valid = hv && !((dy == 0) && (wp == w_));
          int ti = (dy + 1) * 3 + 1 + wp - w_;
          int spn = h2c * 2 + wp;
          // S[spn][d] = sum of the 4 tokens at spatial pos spn
          uint2 sv = *(const uint2*)(VTd + (((2 * spn) ^ swn) << 2));
          float s = bf2f((unsigned short)(sv.x & 0xffff)) + bf2f((unsigned short)(sv.x >> 16))
                  + bf2f((unsigned short)(sv.y & 0xffff)) + bf2f((unsigned short)(sv.y >> 16));
          acc += (valid ? w9[nt][ti] : 0.f) * s;
        }
      }
      const float cwgt = w9[nt][4];
      const f32x4 ov = nt ? oo1 : oo0;
      // V tokens m0+qd*4 .. +3 for the center-weight term (one uint2)
      uint2 vv4 = *(const uint2*)(VTd + ((((m0 >> 1) + 2 * qd) ^ swn) << 2));
      float vf[4] = { bf2f((unsigned short)(vv4.x & 0xffff)), bf2f((unsigned short)(vv4.x >> 16)),
                      bf2f((unsigned short)(vv4.y & 0xffff)), bf2f((unsigned short)(vv4.y >> 16)) };
#pragma unroll
      for (int r = 0; r < 4; r++){
        float res = ov[r] * il[r] + acc + cwgt * vf[r];
        size_t off = (size_t)b * 2097152 + (size_t)h_ * 32768 +
                     (size_t)(jj * 2 + w_) * 512 + (size_t)r * 128 + head * 32 + d;
        outg[off] = res;
      }
    }
  }
}

extern "C" void kernel_launch(void* const* d_in, const int* in_sizes, int n_in,
                              void* d_out, int out_size, void* d_ws, size_t ws_size,
                              hipStream_t stream) {
  (void)in_sizes; (void)n_in; (void)d_ws; (void)ws_size; (void)out_size;
  cswin_attn_kernel<<<dim3(1024), dim3(256), 0, stream>>>(
      (const float*)d_in[0], (const float*)d_in[1], (const float*)d_in[2],
      (const float*)d_in[3], (float*)d_out);
}

// Round 2
// 139.171 us; speedup vs baseline: 1.0349x; 1.0349x over previous
//
#include <hip/hip_runtime.h>
#include <stdint.h>

// CSWin attention, MI355X/gfx950 — r11: kill the PB LDS transpose.
// Shapes: B=2, H=W=64, N=4, DIM=128, HEADS=4, HEAD_DIM=32, SPLIT=2.
// 64 windows x 4 heads, L=512 tokens, D=32. Grid 1024 = (window,head) x 4
// row-quarters; block 256 (4 waves); wave = 32 q-rows (2 m-tiles).
//
// r11 theory: r10 showed the 4th resident block made each block 58% slower
// (VALUBusy 48->40 despite occupancy 23->34): the per-chunk P transpose via
// LDS (write->lgkmcnt0->read, twice, between wave_barriers) is a serial
// round trip whose latency balloons when 16 waves/CU queue on the LDS pipe.
// Changes:
//  * P transpose now fully in-register: butterfly over the 4-lane group
//    {n,n+16,n+32,n+48} — shfl_xor(32) routes the tile bit, shfl_xor(16)
//    routes the source-lane bit, cndmask selects assemble the A-fragments.
//    No barriers, no LDS traffic, no serial waits. PB (8KB) deleted ->
//    LDS 32768.
//  * Output epilogue: nt=0 / nt=1 results computed first, then stored
//    back-to-back per r so both 64B halves of each 128B line coalesce in
//    TCC (r10's WRITE_SIZE was 2.1x output size from split half-line
//    writes being RMW'd).
// Predicted: conflicts <0.6M, WRITE ~17.5MB, VALUBusy 50+%, dur ~50us.

typedef __bf16 bf16x8 __attribute__((ext_vector_type(8)));
typedef float f32x4 __attribute__((ext_vector_type(4)));

#if __has_builtin(__builtin_amdgcn_exp2f)
#define EXP2F __builtin_amdgcn_exp2f
#else
#define EXP2F exp2f
#endif

union U4 { uint4 u; bf16x8 v; unsigned short s[8]; };

__device__ __forceinline__ unsigned fbits(float f){ union{float f;unsigned u;}x; x.f=f; return x.u; }
__device__ __forceinline__ float bf2f(unsigned short h){ union{unsigned u;float f;}x; x.u=((unsigned)h)<<16; return x.f; }
// f32->bf16 round-nearest (ties away), two at once: 2 v_add + 1 v_perm
__device__ __forceinline__ unsigned pk2f(float lo, float hi){
  return __builtin_amdgcn_perm(fbits(hi)+0x8000u, fbits(lo)+0x8000u, 0x07060302u);
}
__device__ __forceinline__ U4 pack8(float4 a, float4 b){
  U4 r;
  r.u.x = pk2f(a.x, a.y); r.u.y = pk2f(a.z, a.w);
  r.u.z = pk2f(b.x, b.y); r.u.w = pk2f(b.z, b.w);
  return r;
}

// In-register P transpose: lane (qd,n) holds s[t][r] = P[q=n][k=t*16+qd*4+r].
// Produces A-frags: ap0 = P[row=n][k=qd*8..+7], ap1 = same for k+32.
// Exchange is within lane group {n, n+16, n+32, n+48}; verified for all qd.
__device__ __forceinline__ void xpose_p(const f32x4* s, bool hiq, bool loq, bool ko,
                                        U4& ap0, U4& ap1)
{
  unsigned w0[2], w1[2], w2[2], w3[2];
  w0[0]=pk2f(s[0][0],s[0][1]); w0[1]=pk2f(s[0][2],s[0][3]);
  w1[0]=pk2f(s[1][0],s[1][1]); w1[1]=pk2f(s[1][2],s[1][3]);
  w2[0]=pk2f(s[2][0],s[2][1]); w2[1]=pk2f(s[2][2],s[2][3]);
  w3[0]=pk2f(s[3][0],s[3][1]); w3[1]=pk2f(s[3][2],s[3][3]);
  // Round 1 (xor 32): keep tiles {l1, l1+2}, receive partner's same tiles.
  unsigned kA[2], kB[2], rA[2], rB[2];
#pragma unroll
  for (int i = 0; i < 2; i++){
    unsigned sA = hiq ? w0[i] : w1[i];   // send tile ~l1
    unsigned sB = hiq ? w2[i] : w3[i];   // send tile ~l1+2
    kA[i] = hiq ? w1[i] : w0[i];         // keep tile l1   (src s1=l1)
    kB[i] = hiq ? w3[i] : w2[i];         // keep tile l1+2 (src s1=l1)
    rA[i] = __shfl_xor(sA, 32);          // tile l1,   src s1=~l1
    rB[i] = __shfl_xor(sB, 32);          // tile l1+2, src s1=~l1
  }
  // Round 2 (xor 16): keep the group with src s1==l0, swap the other.
  unsigned pA[2], pB[2], gA[2], gB[2];
#pragma unroll
  for (int i = 0; i < 2; i++){
    unsigned s2A = ko ? rA[i] : kA[i];
    unsigned s2B = ko ? rB[i] : kB[i];
    gA[i] = __shfl_xor(s2A, 16);         // src (s1=l0, s0=~l0)
    gB[i] = __shfl_xor(s2B, 16);
    pA[i] = ko ? kA[i] : rA[i];          // src (s1=l0, s0=l0)
    pB[i] = ko ? kB[i] : rB[i];
  }
  // Assemble: dwords ordered s0=0 (k+0..3) then s0=1 (k+4..7).
  ap0.u.x = loq ? gA[0] : pA[0];
  ap0.u.y = loq ? gA[1] : pA[1];
  ap0.u.z = loq ? pA[0] : gA[0];
  ap0.u.w = loq ? pA[1] : gA[1];
  ap1.u.x = loq ? gB[0] : pB[0];
  ap1.u.y = loq ? gB[1] : pB[1];
  ap1.u.z = loq ? pB[0] : gB[0];
  ap1.u.w = loq ? pB[1] : gB[1];
}

#define C_SCALE 0.25506953149031837f  // (1/sqrt(32)) * log2(e)
#define M_SHIFT 20.0f                 // fixed log2-domain softmax shift

// LDS: VT bf16 [32 ch][512 tok] swizzled, 1024B/row. Nothing else.
#define VT_OFF 0
#define LDS_BYTES 32768

__global__ __launch_bounds__(256, 4) void cswin_attn_kernel(
    const float* __restrict__ qg,
    const float* __restrict__ kg,
    const float* __restrict__ vg,
    const float* __restrict__ cwg,
    float* __restrict__ outg)
{
  __shared__ __align__(16) unsigned char smem[LDS_BYTES];
  const int tid = threadIdx.x;
  const int lane = tid & 63;
  const int wave = tid >> 6;
  const int qd = lane >> 4;
  const int n  = lane & 15;
  const bool hiq = (lane & 32) != 0;       // l1 = qd>>1
  const bool loq = (lane & 16) != 0;       // l0 = qd&1
  const bool ko  = (hiq == loq);

  // VT swizzle: in-row dword index ^= (row&7)<<2.
  const int swn = (n & 7) << 2;
  const int xb0 = ((4 * qd) ^ swn) << 2;   // byte off of swizzled dword 4qd
  const int xb1 = xb0 ^ 64;                // ... of dword 16+4qd

  const int bh = blockIdx.x & 255;
  const int q4 = blockIdx.x >> 8;     // row-quarter 0..3
  const int head = bh & 3;
  const int bw = bh >> 2;
  const int b  = bw >> 5;
  const int jj = bw & 31;

  // token l: offset = wbase + (l>>3)*32768 + ((l>>2)&1)*512 + (l&3)*128
  const size_t wbase = (size_t)b * 2097152 + (size_t)(jj * 2) * 512 + head * 32;

  // ---- stage V -> VT bf16 (2 tokens per thread, packed pairwise) ----
  {
    int l0 = tid * 2;
    size_t off = wbase + (size_t)(l0 >> 3) * 32768 + (size_t)((l0 >> 2) & 1) * 512 + (l0 & 3) * 128;
    const float* p0 = vg + off;
    unsigned u0[32], u1[32];
#pragma unroll
    for (int c = 0; c < 8; c++){
      float4 a = ((const float4*)p0)[c];
      u0[c*4+0]=fbits(a.x)+0x8000u; u0[c*4+1]=fbits(a.y)+0x8000u;
      u0[c*4+2]=fbits(a.z)+0x8000u; u0[c*4+3]=fbits(a.w)+0x8000u;
    }
#pragma unroll
    for (int c = 0; c < 8; c++){
      float4 a = ((const float4*)(p0 + 128))[c];
      u1[c*4+0]=fbits(a.x)+0x8000u; u1[c*4+1]=fbits(a.y)+0x8000u;
      u1[c*4+2]=fbits(a.z)+0x8000u; u1[c*4+3]=fbits(a.w)+0x8000u;
    }
    // logical dword col = tid (token pair 2*tid, 2*tid+1), row = d
#pragma unroll
    for (int d = 0; d < 32; d++)
      *(unsigned*)(smem + VT_OFF + d * 1024 + ((tid ^ ((d & 7) << 2)) << 2)) =
          __builtin_amdgcn_perm(u1[d], u0[d], 0x07060302u);
  }
  __syncthreads();

  // per-lane elem base for Q/K fragments (token tile*16+n, channels qd*8..+7)
  const size_t lane_base = wbase + (size_t)(n >> 3) * 32768 + (size_t)((n >> 2) & 1) * 512 +
                           (size_t)(n & 3) * 128 + qd * 8;

  const int row0  = q4 * 128 + wave * 32;
  const int tilea = row0 >> 4;          // even; m-tile B = tilea+1
  const int cka   = tilea >> 2;         // chunk holding both diag tiles
  const int ta    = tilea & 3;          // in-chunk tile idx of A's diag

  U4 bqa, bqb;
  {
    const float* qa = qg + lane_base + (size_t)tilea * 65536;
    const float* qb = qa + 65536;
    bqa = pack8(((const float4*)qa)[0], ((const float4*)qa)[1]);
    bqb = pack8(((const float4*)qb)[0], ((const float4*)qb)[1]);
  }

  f32x4 o0a={0,0,0,0}, o1a={0,0,0,0}, o0b={0,0,0,0}, o1b={0,0,0,0};
  float la = 0.f, lb = 0.f;            // per-lane partial softmax sums

  // prefetch chunk 0 K rows (raw f32; packed at use)
  float4 nxt[8];
#pragma unroll
  for (int t = 0; t < 4; t++){
    const float* kp = kg + lane_base + (size_t)t * 65536;
    nxt[2*t] = ((const float4*)kp)[0]; nxt[2*t+1] = ((const float4*)kp)[1];
  }

#pragma unroll 1
  for (int ck = 0; ck < 8; ck++){
    U4 ak[4];
#pragma unroll
    for (int t = 0; t < 4; t++) ak[t] = pack8(nxt[2*t], nxt[2*t+1]);
    if (ck < 7){
#pragma unroll
      for (int t = 0; t < 4; t++){
        const float* kp = kg + lane_base + (size_t)((ck + 1) * 4 + t) * 65536;
        nxt[2*t] = ((const float4*)kp)[0]; nxt[2*t+1] = ((const float4*)kp)[1];
      }
    }

    const f32x4 zero = {0.f,0.f,0.f,0.f};
    f32x4 sa[4], sb[4];
#pragma unroll
    for (int t = 0; t < 4; t++){
      sa[t] = __builtin_amdgcn_mfma_f32_16x16x32_bf16(ak[t].v, bqa.v, zero, 0, 0, 0);
      sb[t] = __builtin_amdgcn_mfma_f32_16x16x32_bf16(ak[t].v, bqb.v, zero, 0, 0, 0);
    }
    if (ck == cka){
      bool dq = (qd == (n >> 2));
#pragma unroll
      for (int r = 0; r < 4; r++)
        if (dq && r != (n & 3)){ sa[ta][r] = -1e30f; sb[ta+1][r] = -1e30f; }
    }

    // ---- fixed-shift softmax: p = exp2(s*C - M); accumulate per-lane l ----
#pragma unroll
    for (int t = 0; t < 4; t++)
#pragma unroll
      for (int r = 0; r < 4; r++){
        float p = EXP2F(__builtin_fmaf(sa[t][r], C_SCALE, -M_SHIFT));
        sa[t][r] = p; la += p;
      }
#pragma unroll
    for (int t = 0; t < 4; t++)
#pragma unroll
      for (int r = 0; r < 4; r++){
        float p = EXP2F(__builtin_fmaf(sb[t][r], C_SCALE, -M_SHIFT));
        sb[t][r] = p; lb += p;
      }

    // ---- V fragments shared by both m-tiles (swizzled VT reads) ----
    const unsigned char* vr0 = smem + VT_OFF + n * 1024 + ck * 128;
    const unsigned char* vr1 = vr0 + 16 * 1024;
    U4 bv00, bv01, bv10, bv11;
    bv00.u = *(const uint4*)(vr0 + xb0);
    bv01.u = *(const uint4*)(vr0 + xb1);
    bv10.u = *(const uint4*)(vr1 + xb0);
    bv11.u = *(const uint4*)(vr1 + xb1);

    // ---- P transpose fully in-register (no LDS, no barriers) ----
    U4 apA0, apA1, apB0, apB1;
    xpose_p(sa, hiq, loq, ko, apA0, apA1);
    xpose_p(sb, hiq, loq, ko, apB0, apB1);

    o0a = __builtin_amdgcn_mfma_f32_16x16x32_bf16(apA0.v, bv00.v, o0a, 0, 0, 0);
    o0a = __builtin_amdgcn_mfma_f32_16x16x32_bf16(apA1.v, bv01.v, o0a, 0, 0, 0);
    o1a = __builtin_amdgcn_mfma_f32_16x16x32_bf16(apA0.v, bv10.v, o1a, 0, 0, 0);
    o1a = __builtin_amdgcn_mfma_f32_16x16x32_bf16(apA1.v, bv11.v, o1a, 0, 0, 0);
    o0b = __builtin_amdgcn_mfma_f32_16x16x32_bf16(apB0.v, bv00.v, o0b, 0, 0, 0);
    o0b = __builtin_amdgcn_mfma_f32_16x16x32_bf16(apB1.v, bv01.v, o0b, 0, 0, 0);
    o1b = __builtin_amdgcn_mfma_f32_16x16x32_bf16(apB0.v, bv10.v, o1b, 0, 0, 0);
    o1b = __builtin_amdgcn_mfma_f32_16x16x32_bf16(apB1.v, bv11.v, o1b, 0, 0, 0);
  }

  // ---- conv weights (global loads overlap the reductions below) ----
  float w9[2][9];
#pragma unroll
  for (int nt = 0; nt < 2; nt++){
    int c = head * 32 + nt * 16 + n;
#pragma unroll
    for (int t9 = 0; t9 < 9; t9++) w9[nt][t9] = cwg[c * 9 + t9];
  }

  // ---- final cross-lane l reduction (once, not per chunk) ----
  la += __shfl_xor(la, 16); la += __shfl_xor(la, 32);
  lb += __shfl_xor(lb, 16); lb += __shfl_xor(lb, 32);

  const float ila = 1.f / la, ilb = 1.f / lb;

  // ---- epilogue: compute both nt halves first, then store adjacently so
  //      each 128B output line's two 64B halves coalesce in TCC ----
#pragma unroll
  for (int mt = 0; mt < 2; mt++){
    const int m0 = row0 + mt * 16;
    const float ilv = mt ? ilb : ila;
    const f32x4 oo0 = mt ? o0b : o0a;
    const f32x4 oo1 = mt ? o1b : o1a;
    float il[4];
#pragma unroll
    for (int r = 0; r < 4; r++) il[r] = __shfl(ilv, qd * 4 + r);

    const int sp = (m0 >> 2) + qd;
    const int h_ = sp >> 1, w_ = sp & 1;

    float accs[2], cw2[2], vfs[2][4];
#pragma unroll
    for (int nt = 0; nt < 2; nt++){
      const int d = nt * 16 + n;
      const unsigned char* VTd = smem + VT_OFF + d * 1024;   // (d&7)==(n&7)
      float acc = 0.f;
#pragma unroll
      for (int dy = -1; dy <= 1; dy++){
        int h2 = h_ + dy;
        bool hv = (h2 >= 0) && (h2 <= 63);
        int h2c = hv ? h2 : h_;   // safe in-range address for masked lanes
#pragma unroll
        for (int wp = 0; wp < 2; wp++){
          bool valid = hv && !((dy == 0) && (wp == w_));
          int ti = (dy + 1) * 3 + 1 + wp - w_;
          int spn = h2c * 2 + wp;
          // S[spn][d] = sum of the 4 tokens at spatial pos spn
          uint2 sv = *(const uint2*)(VTd + (((2 * spn) ^ swn) << 2));
          float s = bf2f((unsigned short)(sv.x & 0xffff)) + bf2f((unsigned short)(sv.x >> 16))
                  + bf2f((unsigned short)(sv.y & 0xffff)) + bf2f((unsigned short)(sv.y >> 16));
          acc += (valid ? w9[nt][ti] : 0.f) * s;
        }
      }
      accs[nt] = acc;
      cw2[nt] = w9[nt][4];
      // V tokens m0+qd*4 .. +3 for the center-weight term (one uint2)
      uint2 vv4 = *(const uint2*)(VTd + ((((m0 >> 1) + 2 * qd) ^ swn) << 2));
      vfs[nt][0] = bf2f((unsigned short)(vv4.x & 0xffff));
      vfs[nt][1] = bf2f((unsigned short)(vv4.x >> 16));
      vfs[nt][2] = bf2f((unsigned short)(vv4.y & 0xffff));
      vfs[nt][3] = bf2f((unsigned short)(vv4.y >> 16));
    }

    const size_t obase = (size_t)b * 2097152 + (size_t)h_ * 32768 +
                         (size_t)(jj * 2 + w_) * 512 + head * 32;
#pragma unroll
    for (int r = 0; r < 4; r++){
      float r0 = oo0[r] * il[r] + accs[0] + cw2[0] * vfs[0][r];
      float r1 = oo1[r] * il[r] + accs[1] + cw2[1] * vfs[1][r];
      outg[obase + (size_t)r * 128 + n]      = r0;   // line half 1
      outg[obase + (size_t)r * 128 + 16 + n] = r1;   // line half 2 (adjacent)
    }
  }
}

extern "C" void kernel_launch(void* const* d_in, const int* in_sizes, int n_in,
                              void* d_out, int out_size, void* d_ws, size_t ws_size,
                              hipStream_t stream) {
  (void)in_sizes; (void)n_in; (void)d_ws; (void)ws_size; (void)out_size;
  cswin_attn_kernel<<<dim3(1024), dim3(256), 0, stream>>>(
      (const float*)d_in[0], (const float*)d_in[1], (const float*)d_in[2],
      (const float*)d_in[3], (float*)d_out);
}

// Round 3
// 134.683 us; speedup vs baseline: 1.0694x; 1.0333x over previous
//
#include <hip/hip_runtime.h>
#include <stdint.h>

// CSWin attention, MI355X/gfx950 — r12: HW repack (cvt_pk + permlane swaps).
// Shapes: B=2, H=W=64, N=4, DIM=128, HEADS=4, HEAD_DIM=32, SPLIT=2.
// 64 windows x 4 heads, L=512 tokens, D=32. Grid 1024 = (window,head) x 4
// row-quarters; block 256 (4 waves); wave = 32 q-rows (2 m-tiles).
//
// r12 theory: r11 still VALU/latency-bound (VALUBusy 48%, Mfma 5%, HBM 11%).
// ~60% of hot-loop VALU was data repacking, and __shfl_xor = ds_bpermute
// (LDS pipe, ~120cy, 2 serial per transpose). Replace with gfx950 HW:
//  * v_cvt_pk_bf16_f32: 1 instr per f32 pair (K-pack 48->16/chunk, P-pack,
//    V-staging 96->32). RTNE instead of ties-away: >= accuracy.
//  * P-relayout via v_permlane32_swap + v_permlane16_swap: derived mapping
//    dest lane (l1,l0) slot (s,j1,j0) <- src lane (l0,j1), tile 2s+l1,
//    dword j0. pls32 then pls16 on pair (w[2s],w[2s+1]) yields both
//    A-frag words: 2 instr/dword-pair, no selects, no DS pipe.
//  * packed-f32 (v_pk_fma/add) for softmax scale-shift + l-accum.
// Predicted: dur ~45-50us, MfmaUtil ~7%, conflicts/FETCH/WRITE ~unchanged.

typedef __bf16 bf16x8 __attribute__((ext_vector_type(8)));
typedef float f32x4 __attribute__((ext_vector_type(4)));
typedef float f32x2 __attribute__((ext_vector_type(2)));

#if __has_builtin(__builtin_amdgcn_exp2f)
#define EXP2F __builtin_amdgcn_exp2f
#else
#define EXP2F exp2f
#endif

union U4 { uint4 u; bf16x8 v; unsigned short s[8]; };

__device__ __forceinline__ float bf2f(unsigned short h){ union{unsigned u;float f;}x; x.u=((unsigned)h)<<16; return x.f; }

// f32 pair -> packed bf16 dword (lo in low half), RTNE. 1 instr.
__device__ __forceinline__ unsigned cvtpk(float lo, float hi){
  unsigned d;
  asm("v_cvt_pk_bf16_f32 %0, %1, %2" : "=v"(d) : "v"(lo), "v"(hi));
  return d;
}
__device__ __forceinline__ U4 pack8(float4 a, float4 b){
  U4 r;
  r.u.x = cvtpk(a.x, a.y); r.u.y = cvtpk(a.z, a.w);
  r.u.z = cvtpk(b.x, b.y); r.u.w = cvtpk(b.z, b.w);
  return r;
}

// permlane swap pair primitives (gfx950). After the call:
//   pls32: a[(l1,l0)] = old(l1? b : a) @ lane(0,l0) ... i.e.
//          a' = w_{l1} @ (0,l0),  b' = w_{l1} @ (1,l0)   (w_0=a, w_1=b)
//   pls16 (within each 32-half): a' = in_{?} @ (l0,0), b' = @ (l0,1)
__device__ __forceinline__ void pls32(unsigned &a, unsigned &b){
#if __has_builtin(__builtin_amdgcn_permlane32_swap)
  auto r = __builtin_amdgcn_permlane32_swap(a, b, false, false);
  a = r[0]; b = r[1];
#else
  unsigned sa_ = __shfl_xor(a, 32), sb_ = __shfl_xor(b, 32);
  bool hi = ((threadIdx.x & 32) != 0);
  unsigned na = hi ? sb_ : a, nb = hi ? b : sa_;
  a = na; b = nb;
#endif
}
__device__ __forceinline__ void pls16(unsigned &a, unsigned &b){
#if __has_builtin(__builtin_amdgcn_permlane16_swap)
  auto r = __builtin_amdgcn_permlane16_swap(a, b, false, false);
  a = r[0]; b = r[1];
#else
  unsigned sa_ = __shfl_xor(a, 16), sb_ = __shfl_xor(b, 16);
  bool hi = ((threadIdx.x & 16) != 0);
  unsigned na = hi ? sb_ : a, nb = hi ? b : sa_;
  a = na; b = nb;
#endif
}

// In-register P transpose. Input: w[t][i] = packed P[q=n][k=16t+4*qd+{2i,2i+1}]
// (qd = this lane's group). Output A-frags: ap0 = P[row=n][k=qd*8..+7],
// ap1 = same for k+32. 8 swaps + 0 selects, all VALU.
__device__ __forceinline__ void xpose_p(const unsigned w[4][2], U4& ap0, U4& ap1)
{
  unsigned a0 = w[0][0], b0 = w[1][0]; pls32(a0, b0); pls16(a0, b0);
  unsigned a1 = w[0][1], b1 = w[1][1]; pls32(a1, b1); pls16(a1, b1);
  ap0.u.x = a0; ap0.u.y = a1; ap0.u.z = b0; ap0.u.w = b1;
  unsigned c0 = w[2][0], d0 = w[3][0]; pls32(c0, d0); pls16(c0, d0);
  unsigned c1 = w[2][1], d1 = w[3][1]; pls32(c1, d1); pls16(c1, d1);
  ap1.u.x = c0; ap1.u.y = c1; ap1.u.z = d0; ap1.u.w = d1;
}

#define C_SCALE 0.25506953149031837f  // (1/sqrt(32)) * log2(e)
#define M_SHIFT 20.0f                 // fixed log2-domain softmax shift

// Fused fixed-shift softmax + bf16 pack: p = exp2(s*C - M), l2 += pairs,
// w[t][i] = packed pairs. Packed-f32 ops where the backend supports them.
__device__ __forceinline__ void sm_pack(const f32x4* s, unsigned w[4][2], f32x2& l2)
{
  const f32x2 m2 = {-M_SHIFT, -M_SHIFT};
#pragma unroll
  for (int t = 0; t < 4; t++){
    f32x2 x0 = {s[t][0], s[t][1]};
    f32x2 x1 = {s[t][2], s[t][3]};
    f32x2 y0 = x0 * C_SCALE + m2;      // v_pk_fma_f32
    f32x2 y1 = x1 * C_SCALE + m2;
    float p0 = EXP2F(y0.x), p1 = EXP2F(y0.y);
    float p2 = EXP2F(y1.x), p3 = EXP2F(y1.y);
    l2 += (f32x2){p0, p1};             // v_pk_add_f32
    l2 += (f32x2){p2, p3};
    w[t][0] = cvtpk(p0, p1);
    w[t][1] = cvtpk(p2, p3);
  }
}

// LDS: VT bf16 [32 ch][512 tok] swizzled, 1024B/row. Nothing else.
#define VT_OFF 0
#define LDS_BYTES 32768

__global__ __launch_bounds__(256, 4) void cswin_attn_kernel(
    const float* __restrict__ qg,
    const float* __restrict__ kg,
    const float* __restrict__ vg,
    const float* __restrict__ cwg,
    float* __restrict__ outg)
{
  __shared__ __align__(16) unsigned char smem[LDS_BYTES];
  const int tid = threadIdx.x;
  const int lane = tid & 63;
  const int wave = tid >> 6;
  const int qd = lane >> 4;
  const int n  = lane & 15;

  // VT swizzle: in-row dword index ^= (row&7)<<2.
  const int swn = (n & 7) << 2;
  const int xb0 = ((4 * qd) ^ swn) << 2;   // byte off of swizzled dword 4qd
  const int xb1 = xb0 ^ 64;                // ... of dword 16+4qd

  const int bh = blockIdx.x & 255;
  const int q4 = blockIdx.x >> 8;     // row-quarter 0..3
  const int head = bh & 3;
  const int bw = bh >> 2;
  const int b  = bw >> 5;
  const int jj = bw & 31;

  // token l: offset = wbase + (l>>3)*32768 + ((l>>2)&1)*512 + (l&3)*128
  const size_t wbase = (size_t)b * 2097152 + (size_t)(jj * 2) * 512 + head * 32;

  // ---- stage V -> VT bf16 (2 tokens per thread, packed pairwise) ----
  {
    int l0 = tid * 2;
    size_t off = wbase + (size_t)(l0 >> 3) * 32768 + (size_t)((l0 >> 2) & 1) * 512 + (l0 & 3) * 128;
    const float* p0 = vg + off;
    float v0[32], v1[32];
#pragma unroll
    for (int c = 0; c < 8; c++){
      float4 a = ((const float4*)p0)[c];
      v0[c*4+0]=a.x; v0[c*4+1]=a.y; v0[c*4+2]=a.z; v0[c*4+3]=a.w;
    }
#pragma unroll
    for (int c = 0; c < 8; c++){
      float4 a = ((const float4*)(p0 + 128))[c];
      v1[c*4+0]=a.x; v1[c*4+1]=a.y; v1[c*4+2]=a.z; v1[c*4+3]=a.w;
    }
    // logical dword col = tid (token pair 2*tid, 2*tid+1), row = d
#pragma unroll
    for (int d = 0; d < 32; d++)
      *(unsigned*)(smem + VT_OFF + d * 1024 + ((tid ^ ((d & 7) << 2)) << 2)) =
          cvtpk(v0[d], v1[d]);
  }
  __syncthreads();

  // per-lane elem base for Q/K fragments (token tile*16+n, channels qd*8..+7)
  const size_t lane_base = wbase + (size_t)(n >> 3) * 32768 + (size_t)((n >> 2) & 1) * 512 +
                           (size_t)(n & 3) * 128 + qd * 8;

  const int row0  = q4 * 128 + wave * 32;
  const int tilea = row0 >> 4;          // even; m-tile B = tilea+1
  const int cka   = tilea >> 2;         // chunk holding both diag tiles
  const int ta    = tilea & 3;          // in-chunk tile idx of A's diag

  U4 bqa, bqb;
  {
    const float* qa = qg + lane_base + (size_t)tilea * 65536;
    const float* qb = qa + 65536;
    bqa = pack8(((const float4*)qa)[0], ((const float4*)qa)[1]);
    bqb = pack8(((const float4*)qb)[0], ((const float4*)qb)[1]);
  }

  f32x4 o0a={0,0,0,0}, o1a={0,0,0,0}, o0b={0,0,0,0}, o1b={0,0,0,0};
  f32x2 la2 = {0.f,0.f}, lb2 = {0.f,0.f};   // packed per-lane softmax sums

  // prefetch chunk 0 K rows (raw f32; packed at use)
  float4 nxt[8];
#pragma unroll
  for (int t = 0; t < 4; t++){
    const float* kp = kg + lane_base + (size_t)t * 65536;
    nxt[2*t] = ((const float4*)kp)[0]; nxt[2*t+1] = ((const float4*)kp)[1];
  }

#pragma unroll 1
  for (int ck = 0; ck < 8; ck++){
    U4 ak[4];
#pragma unroll
    for (int t = 0; t < 4; t++) ak[t] = pack8(nxt[2*t], nxt[2*t+1]);
    if (ck < 7){
#pragma unroll
      for (int t = 0; t < 4; t++){
        const float* kp = kg + lane_base + (size_t)((ck + 1) * 4 + t) * 65536;
        nxt[2*t] = ((const float4*)kp)[0]; nxt[2*t+1] = ((const float4*)kp)[1];
      }
    }

    const f32x4 zero = {0.f,0.f,0.f,0.f};
    f32x4 sa[4], sb[4];
#pragma unroll
    for (int t = 0; t < 4; t++){
      sa[t] = __builtin_amdgcn_mfma_f32_16x16x32_bf16(ak[t].v, bqa.v, zero, 0, 0, 0);
      sb[t] = __builtin_amdgcn_mfma_f32_16x16x32_bf16(ak[t].v, bqb.v, zero, 0, 0, 0);
    }
    if (ck == cka){
      bool dq = (qd == (n >> 2));
#pragma unroll
      for (int r = 0; r < 4; r++)
        if (dq && r != (n & 3)){ sa[ta][r] = -1e30f; sb[ta+1][r] = -1e30f; }
    }

    // ---- fused softmax + pack (p = exp2(s*C - M)) ----
    unsigned wA[4][2], wB[4][2];
    sm_pack(sa, wA, la2);
    sm_pack(sb, wB, lb2);

    // ---- V fragments shared by both m-tiles (swizzled VT reads) ----
    const unsigned char* vr0 = smem + VT_OFF + n * 1024 + ck * 128;
    const unsigned char* vr1 = vr0 + 16 * 1024;
    U4 bv00, bv01, bv10, bv11;
    bv00.u = *(const uint4*)(vr0 + xb0);
    bv01.u = *(const uint4*)(vr0 + xb1);
    bv10.u = *(const uint4*)(vr1 + xb0);
    bv11.u = *(const uint4*)(vr1 + xb1);

    // ---- P transpose fully in-register (permlane swaps, no DS pipe) ----
    U4 apA0, apA1, apB0, apB1;
    xpose_p(wA, apA0, apA1);
    xpose_p(wB, apB0, apB1);

    o0a = __builtin_amdgcn_mfma_f32_16x16x32_bf16(apA0.v, bv00.v, o0a, 0, 0, 0);
    o0a = __builtin_amdgcn_mfma_f32_16x16x32_bf16(apA1.v, bv01.v, o0a, 0, 0, 0);
    o1a = __builtin_amdgcn_mfma_f32_16x16x32_bf16(apA0.v, bv10.v, o1a, 0, 0, 0);
    o1a = __builtin_amdgcn_mfma_f32_16x16x32_bf16(apA1.v, bv11.v, o1a, 0, 0, 0);
    o0b = __builtin_amdgcn_mfma_f32_16x16x32_bf16(apB0.v, bv00.v, o0b, 0, 0, 0);
    o0b = __builtin_amdgcn_mfma_f32_16x16x32_bf16(apB1.v, bv01.v, o0b, 0, 0, 0);
    o1b = __builtin_amdgcn_mfma_f32_16x16x32_bf16(apB0.v, bv10.v, o1b, 0, 0, 0);
    o1b = __builtin_amdgcn_mfma_f32_16x16x32_bf16(apB1.v, bv11.v, o1b, 0, 0, 0);
  }

  // ---- conv weights (global loads overlap the reductions below) ----
  float w9[2][9];
#pragma unroll
  for (int nt = 0; nt < 2; nt++){
    int c = head * 32 + nt * 16 + n;
#pragma unroll
    for (int t9 = 0; t9 < 9; t9++) w9[nt][t9] = cwg[c * 9 + t9];
  }

  // ---- final cross-lane l reduction (once, not per chunk) ----
  float la = la2.x + la2.y, lb = lb2.x + lb2.y;
  la += __shfl_xor(la, 16); la += __shfl_xor(la, 32);
  lb += __shfl_xor(lb, 16); lb += __shfl_xor(lb, 32);

  const float ila = 1.f / la, ilb = 1.f / lb;

  // ---- epilogue: compute both nt halves first, then store adjacently ----
#pragma unroll
  for (int mt = 0; mt < 2; mt++){
    const int m0 = row0 + mt * 16;
    const float ilv = mt ? ilb : ila;
    const f32x4 oo0 = mt ? o0b : o0a;
    const f32x4 oo1 = mt ? o1b : o1a;
    float il[4];
#pragma unroll
    for (int r = 0; r < 4; r++) il[r] = __shfl(ilv, qd * 4 + r);

    const int sp = (m0 >> 2) + qd;
    const int h_ = sp >> 1, w_ = sp & 1;

    float accs[2], cw2[2], vfs[2][4];
#pragma unroll
    for (int nt = 0; nt < 2; nt++){
      const int d = nt * 16 + n;
      const unsigned char* VTd = smem + VT_OFF + d * 1024;   // (d&7)==(n&7)
      float acc = 0.f;
#pragma unroll
      for (int dy = -1; dy <= 1; dy++){
        int h2 = h_ + dy;
        bool hv = (h2 >= 0) && (h2 <= 63);
        int h2c = hv ? h2 : h_;   // safe in-range address for masked lanes
#pragma unroll
        for (int wp = 0; wp < 2; wp++){
          bool valid = hv && !((dy == 0) && (wp == w_));
          int ti = (dy + 1) * 3 + 1 + wp - w_;
          int spn = h2c * 2 + wp;
          // S[spn][d] = sum of the 4 tokens at spatial pos spn
          uint2 sv = *(const uint2*)(VTd + (((2 * spn) ^ swn) << 2));
          float s = bf2f((unsigned short)(sv.x & 0xffff)) + bf2f((unsigned short)(sv.x >> 16))
                  + bf2f((unsigned short)(sv.y & 0xffff)) + bf2f((unsigned short)(sv.y >> 16));
          acc += (valid ? w9[nt][ti] : 0.f) * s;
        }
      }
      accs[nt] = acc;
      cw2[nt] = w9[nt][4];
      // V tokens m0+qd*4 .. +3 for the center-weight term (one uint2)
      uint2 vv4 = *(const uint2*)(VTd + ((((m0 >> 1) + 2 * qd) ^ swn) << 2));
      vfs[nt][0] = bf2f((unsigned short)(vv4.x & 0xffff));
      vfs[nt][1] = bf2f((unsigned short)(vv4.x >> 16));
      vfs[nt][2] = bf2f((unsigned short)(vv4.y & 0xffff));
      vfs[nt][3] = bf2f((unsigned short)(vv4.y >> 16));
    }

    const size_t obase = (size_t)b * 2097152 + (size_t)h_ * 32768 +
                         (size_t)(jj * 2 + w_) * 512 + head * 32;
#pragma unroll
    for (int r = 0; r < 4; r++){
      float r0 = oo0[r] * il[r] + accs[0] + cw2[0] * vfs[0][r];
      float r1 = oo1[r] * il[r] + accs[1] + cw2[1] * vfs[1][r];
      outg[obase + (size_t)r * 128 + n]      = r0;   // line half 1
      outg[obase + (size_t)r * 128 + 16 + n] = r1;   // line half 2 (adjacent)
    }
  }
}

extern "C" void kernel_launch(void* const* d_in, const int* in_sizes, int n_in,
                              void* d_out, int out_size, void* d_ws, size_t ws_size,
                              hipStream_t stream) {
  (void)in_sizes; (void)n_in; (void)d_ws; (void)ws_size; (void)out_size;
  cswin_attn_kernel<<<dim3(1024), dim3(256), 0, stream>>>(
      (const float*)d_in[0], (const float*)d_in[1], (const float*)d_in[2],
      (const float*)d_in[3], (float*)d_out);
}